// Round 16
// baseline (51.350 us; speedup 1.0000x reference)
//
#include <hip/hip_runtime.h>
#include <hip/hip_bf16.h>

// SubjectSpecificProjection: per-subject 2-layer MLP (256->512->512) + L2 normalize.
// R15: fused (R12 base, best=49.9us) + weights via global_load_lds from PACKED
//      source into WAVE-PRIVATE LDS chunks -> zero barriers in the weight path
//      (each wave stages+reads only its own 4KB slot; wave-level vmcnt waits
//      don't stall other waves). Theory: direct loads serialize on L1 miss-fill
//      (~10B/cy/CU, all R1-R12 data); gload_lds bypasses L1 (~22B/cy, m97).
//      M=112 so LDS fits: Hs 116.5K + Wl 32K + misc ~= 154K. 8 waves x 64 cols,
//      acc[7][4], no wave duplication.

#define BATCH 16384
#define EEG 256
#define CLIP 512
#define NSUB 13

// meta layout (ints):
#define M_BCNT 0        // [64][13]
#define M_SOFF 832      // [14] sample offsets per subject
#define M_TOT  846      // [13]
#define M_C112 859      // [14] 112-row chunk offsets
#define M_IDX  896      // [16384]

typedef unsigned short u16;
typedef __attribute__((ext_vector_type(8))) short short8;
typedef __attribute__((ext_vector_type(4))) float f32x4;

__device__ __forceinline__ u16 f2bf(float f) {
    union { float f; unsigned int u; } v; v.f = f;
    unsigned int u = v.u;
    unsigned int r = (u + 0x7FFFu + ((u >> 16) & 1u)) >> 16;   // RNE
    return (u16)r;
}

// ---- weight convert + pack (R7 layout) + fused histogram ----
// chunk(s,g,t) = 2048 u16 [slot(4)][colin(64)][e(8)]; element =
//   W[s][k = t*32 + slot*8 + e][n = g*64 + colin].
__global__ __launch_bounds__(256) void convert_pack(
    const float* __restrict__ W1, const float* __restrict__ W2,
    u16* __restrict__ w1p, u16* __restrict__ w2p,
    const int* __restrict__ sid, int* __restrict__ meta) {
    __shared__ u16 T[64][72];
    __shared__ int hh[NSUB];
    int b = blockIdx.x;
    const float* src; u16* dstbase; int ksteps;
    int s, kt, g;
    if (b < 416) {                     // W1: 13 x (4 kt)x(8 g)
        s = b >> 5; int t = b & 31;
        kt = t >> 3; g = t & 7;
        ksteps = 8;
        src = W1 + (size_t)s * EEG * CLIP;
        dstbase = w1p + (size_t)s * CLIP * EEG;
    } else {                           // W2: 13 x (8 kt)x(8 g)
        b -= 416; s = b >> 6; int t = b & 63;
        kt = t >> 3; g = t & 7;
        ksteps = 16;
        src = W2 + (size_t)s * CLIP * CLIP;
        dstbase = w2p + (size_t)s * CLIP * CLIP;
    }
    int k0 = kt << 6, n0 = g << 6;
    int tid = threadIdx.x;
    int rk = tid >> 2;
    int cg = (tid & 3) << 4;
    const float4* p4 = reinterpret_cast<const float4*>(src + (size_t)(k0 + rk) * CLIP + n0 + cg);
    #pragma unroll
    for (int jj = 0; jj < 4; ++jj) {
        float4 v = p4[jj];
        T[cg + jj * 4 + 0][rk] = f2bf(v.x);
        T[cg + jj * 4 + 1][rk] = f2bf(v.y);
        T[cg + jj * 4 + 2][rk] = f2bf(v.z);
        T[cg + jj * 4 + 3][rk] = f2bf(v.w);
    }
    __syncthreads();
    int colin = tid & 63, sl = (tid >> 6) & 3;
    #pragma unroll
    for (int half = 0; half < 2; ++half) {
        int t = kt * 2 + half;
        u16* dst = dstbase + ((size_t)(g * ksteps + t)) * 2048 + sl * 512 + colin * 8;
        *reinterpret_cast<short8*>(dst) =
            *reinterpret_cast<const short8*>(&T[colin][half * 32 + sl * 8]);
    }
    if (blockIdx.x < 64) {             // fused histogram
        if (tid < NSUB) hh[tid] = 0;
        __syncthreads();
        atomicAdd(&hh[sid[blockIdx.x * 256 + tid]], 1);
        __syncthreads();
        if (tid < NSUB) meta[M_BCNT + blockIdx.x * NSUB + tid] = hh[tid];
    }
}

// ---- scan + scatter in one kernel ----
__global__ __launch_bounds__(256) void scanscatter_k(
    const int* __restrict__ sid, int* __restrict__ meta) {
    __shared__ int cnt[64][NSUB];
    __shared__ int so[NSUB + 1], myoff[NSUB], tot[NSUB];
    __shared__ int h[NSUB];
    int tid = threadIdx.x;
    for (int i = tid; i < 64 * NSUB; i += 256)
        cnt[i / NSUB][i % NSUB] = meta[M_BCNT + i];
    if (tid < NSUB) h[tid] = 0;
    __syncthreads();
    if (tid < NSUB) {
        int run = 0, mine = 0;
        for (int b = 0; b < 64; ++b) {
            if (b == (int)blockIdx.x) mine = run;
            run += cnt[b][tid];
        }
        tot[tid] = run; myoff[tid] = mine;
    }
    __syncthreads();
    if (tid == 0) {
        int off = 0;
        for (int s = 0; s < NSUB; ++s) { so[s] = off; off += tot[s]; }
        so[NSUB] = off;
    }
    __syncthreads();
    if (blockIdx.x == 0) {
        if (tid < NSUB + 1) meta[M_SOFF + tid] = so[tid];
        if (tid < NSUB) meta[M_TOT + tid] = tot[tid];
        if (tid == 0) {
            int c112 = 0;
            for (int s = 0; s < NSUB; ++s) {
                meta[M_C112 + s] = c112;
                c112 += (tot[s] + 111) / 112;
            }
            meta[M_C112 + NSUB] = c112;
        }
    }
    int i = blockIdx.x * 256 + tid;
    int s = sid[i];
    int r = atomicAdd(&h[s], 1);
    meta[M_IDX + so[s] + myoff[s] + r] = i;
}

// ---- fused MLP: M=112 rows, 512 thr / 8 waves x 64 cols, W via wave-private
//      global_load_lds (no barriers in the weight path) ----
__global__ __launch_bounds__(512) void mlp_k(
    const float* __restrict__ X, const float* __restrict__ b1,
    const float* __restrict__ b2, const u16* __restrict__ w1p,
    const u16* __restrict__ w2p, const int* __restrict__ meta,
    float* __restrict__ out) {

    __shared__ u16 Hs[112 * 520];      // 116.5 KB; head doubles as Xc[112][72]
    __shared__ u16 Wl[8 * 2048];       // 32 KB: wave-private 4 KB chunks
    __shared__ float partial[112 * 8]; // 3.5 KB
    __shared__ float scalev[112];
    __shared__ int info[4];
    __shared__ int rowidx[112];
    __shared__ int cobuf[14], sobuf[14], totbuf[NSUB];

    int tid = threadIdx.x;

    // bijective XCD swizzle (m204)
    int nwg = gridDim.x;
    int q = nwg >> 3, r = nwg & 7;
    int xcd = blockIdx.x & 7, idx = blockIdx.x >> 3;
    int bid = (xcd < r) ? xcd * (q + 1) + idx : r * (q + 1) + (xcd - r) * q + idx;

    if (tid < 14) { cobuf[tid] = meta[M_C112 + tid]; sobuf[tid] = meta[M_SOFF + tid]; }
    if (tid < NSUB) totbuf[tid] = meta[M_TOT + tid];
    __syncthreads();
    if (tid == 0) {
        int total = cobuf[NSUB];
        if (bid < total) {
            int s = 0;
            while (s < NSUB && !(bid >= cobuf[s] && bid < cobuf[s + 1])) s++;
            int chunk = bid - cobuf[s];
            info[0] = s;
            info[1] = sobuf[s] + chunk * 112;
            info[2] = min(112, totbuf[s] - chunk * 112);
        } else info[0] = -1;
    }
    __syncthreads();
    if (info[0] < 0) return;
    int s = info[0], rowbase = info[1], nrows = info[2];
    if (tid < 112) rowidx[tid] = meta[M_IDX + rowbase + min(tid, nrows - 1)];

    int wave = tid >> 6, lane = tid & 63;
    int c = lane & 15, gl = lane >> 4;
    int col0 = wave * 64;              // this wave's 64 cols (both layers)
    const u16* w1c = w1p + (size_t)s * CLIP * EEG + (size_t)wave * 8 * 2048;
    const u16* w2c = w2p + (size_t)s * CLIP * CLIP + (size_t)wave * 16 * 2048;
    u16* wl = &Wl[wave * 2048];        // wave-private LDS slot

    // stage one packed 4KB chunk into this wave's slot (dest wave-uniform+lane*16)
#define STAGE_LDS(srcp) do {                                                     \
        _Pragma("unroll")                                                        \
        for (int _it = 0; _it < 4; ++_it)                                        \
            __builtin_amdgcn_global_load_lds(                                    \
                (const __attribute__((address_space(1))) unsigned int*)          \
                    ((srcp) + _it * 512 + lane * 8),                             \
                (__attribute__((address_space(3))) unsigned int*)(wl + _it * 512), \
                16, 0, 0);                                                       \
    } while (0)

    u16* Xc = Hs;                      // alias; temporally separated

    // ---- layer 1: H = relu(X @ W1 + b1), X staged in 64-wide K-chunks ----
    f32x4 acc[7][4];
    #pragma unroll
    for (int mi = 0; mi < 7; ++mi)
        #pragma unroll
        for (int ni = 0; ni < 4; ++ni)
            acc[mi][ni] = (f32x4){0.f, 0.f, 0.f, 0.f};

    int srow = min(tid >> 2, 111), sq4 = tid & 3;   // 4 thr/row (dup rows benign)

    for (int kc = 0; kc < 4; ++kc) {
        __syncthreads();
        {   // stage 112x64 X chunk, fp32 -> bf16
            const float4* xp = reinterpret_cast<const float4*>(
                X + (size_t)rowidx[srow] * EEG) + kc * 16 + sq4 * 4;
            u16* xd = &Xc[srow * 72 + sq4 * 16];
            #pragma unroll
            for (int j = 0; j < 4; ++j) {
                float4 v = xp[j];
                union { u16 u[4]; uint2 qq; } pk;
                pk.u[0] = f2bf(v.x); pk.u[1] = f2bf(v.y);
                pk.u[2] = f2bf(v.z); pk.u[3] = f2bf(v.w);
                *reinterpret_cast<uint2*>(&xd[j * 4]) = pk.qq;
            }
        }
        __syncthreads();
        #pragma unroll
        for (int half = 0; half < 2; ++half) {
            int t = kc * 2 + half;
            STAGE_LDS(w1c + (size_t)t * 2048);
            asm volatile("s_waitcnt vmcnt(0)" ::: "memory");
            __builtin_amdgcn_sched_barrier(0);
            short8 bb[4], a[7];
            #pragma unroll
            for (int ni = 0; ni < 4; ++ni)
                bb[ni] = *reinterpret_cast<const short8*>(&wl[gl * 512 + (ni * 16 + c) * 8]);
            #pragma unroll
            for (int mi = 0; mi < 7; ++mi)
                a[mi] = *reinterpret_cast<const short8*>(
                    &Xc[(mi * 16 + c) * 72 + half * 32 + gl * 8]);
            #pragma unroll
            for (int mi = 0; mi < 7; ++mi)
                #pragma unroll
                for (int ni = 0; ni < 4; ++ni)
                    acc[mi][ni] = __builtin_amdgcn_mfma_f32_16x16x32_bf16(a[mi], bb[ni], acc[mi][ni], 0, 0, 0);
        }
    }
    __syncthreads();   // all waves done reading Xc (head of Hs)

    // bias + relu -> Hs (stride 520)
    {
        float bias1[4];
        #pragma unroll
        for (int ni = 0; ni < 4; ++ni) bias1[ni] = b1[s * CLIP + col0 + ni * 16 + c];
        #pragma unroll
        for (int mi = 0; mi < 7; ++mi)
            #pragma unroll
            for (int ni = 0; ni < 4; ++ni)
                #pragma unroll
                for (int i = 0; i < 4; ++i) {
                    float h = fmaxf(acc[mi][ni][i] + bias1[ni], 0.f);
                    Hs[(mi * 16 + gl * 4 + i) * 520 + col0 + ni * 16 + c] = f2bf(h);
                }
    }
    __syncthreads();

    // ---- layer 2: Y = H @ W2 + b2. Barrier-free, wave-private W pipeline ----
    #pragma unroll
    for (int mi = 0; mi < 7; ++mi)
        #pragma unroll
        for (int ni = 0; ni < 4; ++ni)
            acc[mi][ni] = (f32x4){0.f, 0.f, 0.f, 0.f};

    STAGE_LDS(w2c);   // t = 0
    for (int t = 0; t < 16; ++t) {
        asm volatile("s_waitcnt vmcnt(0)" ::: "memory");
        __builtin_amdgcn_sched_barrier(0);
        short8 bb[4];
        #pragma unroll
        for (int ni = 0; ni < 4; ++ni)
            bb[ni] = *reinterpret_cast<const short8*>(&wl[gl * 512 + (ni * 16 + c) * 8]);
        // bb captured -> safe to overwrite slot with next chunk; overlap with MFMAs
        asm volatile("s_waitcnt lgkmcnt(0)" ::: "memory");
        __builtin_amdgcn_sched_barrier(0);
        if (t < 15) STAGE_LDS(w2c + (size_t)(t + 1) * 2048);
        short8 a[7];
        #pragma unroll
        for (int mi = 0; mi < 7; ++mi)
            a[mi] = *reinterpret_cast<const short8*>(
                &Hs[(mi * 16 + c) * 520 + t * 32 + gl * 8]);
        #pragma unroll
        for (int mi = 0; mi < 7; ++mi)
            #pragma unroll
            for (int ni = 0; ni < 4; ++ni)
                acc[mi][ni] = __builtin_amdgcn_mfma_f32_16x16x32_bf16(a[mi], bb[ni], acc[mi][ni], 0, 0, 0);
    }
#undef STAGE_LDS

    // bias + squared row-sums (this wave's 64 cols of all 112 rows)
    float sq[7][4];
    {
        float bias2[4];
        #pragma unroll
        for (int ni = 0; ni < 4; ++ni) bias2[ni] = b2[s * CLIP + col0 + ni * 16 + c];
        #pragma unroll
        for (int mi = 0; mi < 7; ++mi)
            #pragma unroll
            for (int i = 0; i < 4; ++i) sq[mi][i] = 0.f;
        #pragma unroll
        for (int mi = 0; mi < 7; ++mi)
            #pragma unroll
            for (int ni = 0; ni < 4; ++ni)
                #pragma unroll
                for (int i = 0; i < 4; ++i) {
                    float v = acc[mi][ni][i] + bias2[ni];
                    acc[mi][ni][i] = v;
                    sq[mi][i] += v * v;
                }
    }
    #pragma unroll
    for (int m = 1; m < 16; m <<= 1)
        #pragma unroll
        for (int mi = 0; mi < 7; ++mi)
            #pragma unroll
            for (int i = 0; i < 4; ++i)
                sq[mi][i] += __shfl_xor(sq[mi][i], m);

    if (c == 0) {
        #pragma unroll
        for (int mi = 0; mi < 7; ++mi)
            #pragma unroll
            for (int i = 0; i < 4; ++i)
                partial[(mi * 16 + gl * 4 + i) * 8 + wave] = sq[mi][i];
    }
    __syncthreads();
    if (tid < 112) {
        float t = 0.f;
        #pragma unroll
        for (int w = 0; w < 8; ++w) t += partial[tid * 8 + w];
        scalev[tid] = 1.f / fmaxf(sqrtf(t), 1e-12f);
    }
    __syncthreads();

    #pragma unroll
    for (int mi = 0; mi < 7; ++mi)
        #pragma unroll
        for (int i = 0; i < 4; ++i) {
            int row = mi * 16 + gl * 4 + i;
            if (row < nrows) {
                float sc = scalev[row];
                float* op = out + (size_t)rowidx[row] * CLIP + col0 + c;
                #pragma unroll
                for (int ni = 0; ni < 4; ++ni)
                    __builtin_nontemporal_store(acc[mi][ni][i] * sc, op + ni * 16);
            }
        }
}

extern "C" void kernel_launch(void* const* d_in, const int* in_sizes, int n_in,
                              void* d_out, int out_size, void* d_ws, size_t ws_size,
                              hipStream_t stream) {
    const float* eeg = (const float*)d_in[0];
    const int* sid   = (const int*)d_in[1];
    const float* W1  = (const float*)d_in[2];
    const float* b1  = (const float*)d_in[3];
    const float* W2  = (const float*)d_in[4];
    const float* b2  = (const float*)d_in[5];
    float* out = (float*)d_out;

    u16* w1p = (u16*)d_ws;                                   // 3.4 MB (packed)
    u16* w2p = w1p + (size_t)NSUB * CLIP * EEG;              // 6.8 MB (packed)
    int* meta = (int*)(w2p + (size_t)NSUB * CLIP * CLIP);    // ~68 KB

    convert_pack<<<1248, 256, 0, stream>>>(W1, W2, w1p, w2p, sid, meta);
    scanscatter_k<<<64, 256, 0, stream>>>(sid, meta);
    mlp_k<<<BATCH / 112 + NSUB + 1, 512, 0, stream>>>(eeg, b1, b2, w1p, w2p, meta, out);
}

// Round 17
// 44.118 us; speedup vs baseline: 1.1639x; 1.1639x over previous
//
#include <hip/hip_runtime.h>
#include <hip/hip_bf16.h>

// SubjectSpecificProjection: per-subject 2-layer MLP (256->512->512) + L2 normalize.
// R17: depth-2 wave-private W pipeline with counted vmcnt(4) (never 0 mid-loop),
//      unified 24-stage W1->W2 stream surviving the H handoff, and RAW s_barrier
//      (+lgkmcnt only) for X/H staging so barriers don't drain vmcnt prefetches
//      (compiler __syncthreads emits vmcnt(0) drain). M=80 (LDS: Hs 83.2K +
//      Wl 64K + misc ~= 152K), acc[5][4], 218 blocks, one round.

#define BATCH 16384
#define EEG 256
#define CLIP 512
#define NSUB 13

// meta layout (ints):
#define M_BCNT 0        // [64][13]
#define M_SOFF 832      // [14] sample offsets per subject
#define M_TOT  846      // [13]
#define M_C80  859      // [14] 80-row chunk offsets
#define M_IDX  896      // [16384]

typedef unsigned short u16;
typedef __attribute__((ext_vector_type(8))) short short8;
typedef __attribute__((ext_vector_type(4))) float f32x4;

__device__ __forceinline__ u16 f2bf(float f) {
    union { float f; unsigned int u; } v; v.f = f;
    unsigned int u = v.u;
    unsigned int r = (u + 0x7FFFu + ((u >> 16) & 1u)) >> 16;   // RNE
    return (u16)r;
}

__device__ __forceinline__ void raw_barrier_lgkm() {
    asm volatile("s_waitcnt lgkmcnt(0)" ::: "memory");
    __builtin_amdgcn_sched_barrier(0);
    __builtin_amdgcn_s_barrier();
    __builtin_amdgcn_sched_barrier(0);
}

// ---- weight convert + pack (R7 layout) + fused histogram ----
// chunk(s,g,t) = 2048 u16 [slot(4)][colin(64)][e(8)]; element =
//   W[s][k = t*32 + slot*8 + e][n = g*64 + colin].
__global__ __launch_bounds__(256) void convert_pack(
    const float* __restrict__ W1, const float* __restrict__ W2,
    u16* __restrict__ w1p, u16* __restrict__ w2p,
    const int* __restrict__ sid, int* __restrict__ meta) {
    __shared__ u16 T[64][72];
    __shared__ int hh[NSUB];
    int b = blockIdx.x;
    const float* src; u16* dstbase; int ksteps;
    int s, kt, g;
    if (b < 416) {                     // W1: 13 x (4 kt)x(8 g)
        s = b >> 5; int t = b & 31;
        kt = t >> 3; g = t & 7;
        ksteps = 8;
        src = W1 + (size_t)s * EEG * CLIP;
        dstbase = w1p + (size_t)s * CLIP * EEG;
    } else {                           // W2: 13 x (8 kt)x(8 g)
        b -= 416; s = b >> 6; int t = b & 63;
        kt = t >> 3; g = t & 7;
        ksteps = 16;
        src = W2 + (size_t)s * CLIP * CLIP;
        dstbase = w2p + (size_t)s * CLIP * CLIP;
    }
    int k0 = kt << 6, n0 = g << 6;
    int tid = threadIdx.x;
    int rk = tid >> 2;
    int cg = (tid & 3) << 4;
    const float4* p4 = reinterpret_cast<const float4*>(src + (size_t)(k0 + rk) * CLIP + n0 + cg);
    #pragma unroll
    for (int jj = 0; jj < 4; ++jj) {
        float4 v = p4[jj];
        T[cg + jj * 4 + 0][rk] = f2bf(v.x);
        T[cg + jj * 4 + 1][rk] = f2bf(v.y);
        T[cg + jj * 4 + 2][rk] = f2bf(v.z);
        T[cg + jj * 4 + 3][rk] = f2bf(v.w);
    }
    __syncthreads();
    int colin = tid & 63, sl = (tid >> 6) & 3;
    #pragma unroll
    for (int half = 0; half < 2; ++half) {
        int t = kt * 2 + half;
        u16* dst = dstbase + ((size_t)(g * ksteps + t)) * 2048 + sl * 512 + colin * 8;
        *reinterpret_cast<short8*>(dst) =
            *reinterpret_cast<const short8*>(&T[colin][half * 32 + sl * 8]);
    }
    if (blockIdx.x < 64) {             // fused histogram
        if (tid < NSUB) hh[tid] = 0;
        __syncthreads();
        atomicAdd(&hh[sid[blockIdx.x * 256 + tid]], 1);
        __syncthreads();
        if (tid < NSUB) meta[M_BCNT + blockIdx.x * NSUB + tid] = hh[tid];
    }
}

// ---- scan + scatter in one kernel ----
__global__ __launch_bounds__(256) void scanscatter_k(
    const int* __restrict__ sid, int* __restrict__ meta) {
    __shared__ int cnt[64][NSUB];
    __shared__ int so[NSUB + 1], myoff[NSUB], tot[NSUB];
    __shared__ int h[NSUB];
    int tid = threadIdx.x;
    for (int i = tid; i < 64 * NSUB; i += 256)
        cnt[i / NSUB][i % NSUB] = meta[M_BCNT + i];
    if (tid < NSUB) h[tid] = 0;
    __syncthreads();
    if (tid < NSUB) {
        int run = 0, mine = 0;
        for (int b = 0; b < 64; ++b) {
            if (b == (int)blockIdx.x) mine = run;
            run += cnt[b][tid];
        }
        tot[tid] = run; myoff[tid] = mine;
    }
    __syncthreads();
    if (tid == 0) {
        int off = 0;
        for (int s = 0; s < NSUB; ++s) { so[s] = off; off += tot[s]; }
        so[NSUB] = off;
    }
    __syncthreads();
    if (blockIdx.x == 0) {
        if (tid < NSUB + 1) meta[M_SOFF + tid] = so[tid];
        if (tid < NSUB) meta[M_TOT + tid] = tot[tid];
        if (tid == 0) {
            int c80 = 0;
            for (int s = 0; s < NSUB; ++s) {
                meta[M_C80 + s] = c80;
                c80 += (tot[s] + 79) / 80;
            }
            meta[M_C80 + NSUB] = c80;
        }
    }
    int i = blockIdx.x * 256 + tid;
    int s = sid[i];
    int r = atomicAdd(&h[s], 1);
    meta[M_IDX + so[s] + myoff[s] + r] = i;
}

// ---- fused MLP: M=80, 512 thr / 8 waves x 64 cols, depth-2 wave-private W DMA ----
__global__ __launch_bounds__(512) void mlp_k(
    const float* __restrict__ X, const float* __restrict__ b1,
    const float* __restrict__ b2, const u16* __restrict__ w1p,
    const u16* __restrict__ w2p, const int* __restrict__ meta,
    float* __restrict__ out) {

    __shared__ u16 Hs[80 * 520];       // 83.2 KB; head doubles as Xc[80][72]
    __shared__ u16 Wl[8 * 4096];       // 64 KB: wave-private 2x4KB double buffer
    __shared__ float partial[80 * 8];  // 2.5 KB
    __shared__ float scalev[80];
    __shared__ int info[4];
    __shared__ int rowidx[80];
    __shared__ int cobuf[14], sobuf[14], totbuf[NSUB];

    int tid = threadIdx.x;

    // bijective XCD swizzle (m204)
    int nwg = gridDim.x;
    int q = nwg >> 3, r = nwg & 7;
    int xcd = blockIdx.x & 7, idx = blockIdx.x >> 3;
    int bid = (xcd < r) ? xcd * (q + 1) + idx : r * (q + 1) + (xcd - r) * q + idx;

    if (tid < 14) { cobuf[tid] = meta[M_C80 + tid]; sobuf[tid] = meta[M_SOFF + tid]; }
    if (tid < NSUB) totbuf[tid] = meta[M_TOT + tid];
    __syncthreads();
    if (tid == 0) {
        int total = cobuf[NSUB];
        if (bid < total) {
            int s = 0;
            while (s < NSUB && !(bid >= cobuf[s] && bid < cobuf[s + 1])) s++;
            int chunk = bid - cobuf[s];
            info[0] = s;
            info[1] = sobuf[s] + chunk * 80;
            info[2] = min(80, totbuf[s] - chunk * 80);
        } else info[0] = -1;
    }
    __syncthreads();
    if (info[0] < 0) return;
    int s = info[0], rowbase = info[1], nrows = info[2];
    if (tid < 80) rowidx[tid] = meta[M_IDX + rowbase + min(tid, nrows - 1)];

    int wave = tid >> 6, lane = tid & 63;
    int c = lane & 15, gl = lane >> 4;
    int col0 = wave * 64;              // this wave's 64 cols (both layers)
    const u16* w1c = w1p + (size_t)s * CLIP * EEG + (size_t)wave * 8 * 2048;
    const u16* w2c = w2p + (size_t)s * CLIP * CLIP + (size_t)wave * 16 * 2048;
    u16* wl = &Wl[wave * 4096];        // wave-private: 2 bufs x 2048 u16

    // global stage g (0..23): src = g<8 ? w1 chunk g : w2 chunk g-8; buf = g&1.
#define STAGE_G(g) do {                                                          \
        const u16* _src = ((g) < 8) ? (w1c + (size_t)(g) * 2048)                 \
                                    : (w2c + (size_t)((g) - 8) * 2048);          \
        u16* _dst = wl + (((g) & 1) ? 2048 : 0);                                 \
        _Pragma("unroll")                                                        \
        for (int _it = 0; _it < 4; ++_it)                                        \
            __builtin_amdgcn_global_load_lds(                                    \
                (const __attribute__((address_space(1))) unsigned int*)          \
                    (_src + _it * 512 + lane * 8),                               \
                (__attribute__((address_space(3))) unsigned int*)(_dst + _it * 512), \
                16, 0, 0);                                                       \
    } while (0)

    // prologue: stages 0,1 in flight (8 vmem ops)
    STAGE_G(0);
    STAGE_G(1);

    u16* Xc = Hs;                      // alias; temporally separated

    f32x4 acc[5][4];
    #pragma unroll
    for (int mi = 0; mi < 5; ++mi)
        #pragma unroll
        for (int ni = 0; ni < 4; ++ni)
            acc[mi][ni] = (f32x4){0.f, 0.f, 0.f, 0.f};

    int srow = min(tid >> 2, 79), sq4 = tid & 3;   // 4 thr/row (rows>=80 clamp)

    // ---- layer 1: 4 X-chunks x 2 half-steps; raw barriers (no vmcnt drain) ----
    for (int kc = 0; kc < 4; ++kc) {
        raw_barrier_lgkm();            // prev ds_reads of Xc done (+rowidx visible)
        {   // stage 80x64 X chunk, fp32 -> bf16
            const float4* xp = reinterpret_cast<const float4*>(
                X + (size_t)rowidx[srow] * EEG) + kc * 16 + sq4 * 4;
            u16* xd = &Xc[srow * 72 + sq4 * 16];
            #pragma unroll
            for (int j = 0; j < 4; ++j) {
                float4 v = xp[j];
                union { u16 u[4]; uint2 qq; } pk;
                pk.u[0] = f2bf(v.x); pk.u[1] = f2bf(v.y);
                pk.u[2] = f2bf(v.z); pk.u[3] = f2bf(v.w);
                *reinterpret_cast<uint2*>(&xd[j * 4]) = pk.qq;
            }
        }
        raw_barrier_lgkm();            // Xc writes visible; W prefetch survives
        #pragma unroll
        for (int half = 0; half < 2; ++half) {
            int t = kc * 2 + half;     // global stage t (0..7)
            asm volatile("s_waitcnt vmcnt(4)" ::: "memory");   // stage t done
            __builtin_amdgcn_sched_barrier(0);
            short8 bb[4];
            u16* wb = wl + ((t & 1) ? 2048 : 0);
            #pragma unroll
            for (int ni = 0; ni < 4; ++ni)
                bb[ni] = *reinterpret_cast<const short8*>(&wb[gl * 512 + (ni * 16 + c) * 8]);
            asm volatile("s_waitcnt lgkmcnt(0)" ::: "memory"); // bb in regs
            __builtin_amdgcn_sched_barrier(0);
            STAGE_G(t + 2);            // crosses into W2 at t>=6
            short8 a[5];
            #pragma unroll
            for (int mi = 0; mi < 5; ++mi)
                a[mi] = *reinterpret_cast<const short8*>(
                    &Xc[(mi * 16 + c) * 72 + half * 32 + gl * 8]);
            #pragma unroll
            for (int mi = 0; mi < 5; ++mi)
                #pragma unroll
                for (int ni = 0; ni < 4; ++ni)
                    acc[mi][ni] = __builtin_amdgcn_mfma_f32_16x16x32_bf16(a[mi], bb[ni], acc[mi][ni], 0, 0, 0);
        }
    }
    raw_barrier_lgkm();                // all Xc reads done before Hs overwrite

    // bias + relu -> Hs (stride 520); W2 stages 8,9 already in flight
    {
        float bias1[4];
        #pragma unroll
        for (int ni = 0; ni < 4; ++ni) bias1[ni] = b1[s * CLIP + col0 + ni * 16 + c];
        #pragma unroll
        for (int mi = 0; mi < 5; ++mi)
            #pragma unroll
            for (int ni = 0; ni < 4; ++ni)
                #pragma unroll
                for (int i = 0; i < 4; ++i) {
                    float h = fmaxf(acc[mi][ni][i] + bias1[ni], 0.f);
                    Hs[(mi * 16 + gl * 4 + i) * 520 + col0 + ni * 16 + c] = f2bf(h);
                }
    }
    raw_barrier_lgkm();                // Hs visible to all waves

    // ---- layer 2: 16 steps, barrier-free, depth-2 counted vmcnt ----
    #pragma unroll
    for (int mi = 0; mi < 5; ++mi)
        #pragma unroll
        for (int ni = 0; ni < 4; ++ni)
            acc[mi][ni] = (f32x4){0.f, 0.f, 0.f, 0.f};

    for (int tt = 0; tt < 16; ++tt) {  // consumes global stage 8+tt
        if (tt < 15) asm volatile("s_waitcnt vmcnt(4)" ::: "memory");
        else         asm volatile("s_waitcnt vmcnt(0)" ::: "memory");
        __builtin_amdgcn_sched_barrier(0);
        short8 bb[4];
        u16* wb = wl + ((tt & 1) ? 2048 : 0);   // (8+tt)&1 == tt&1
        #pragma unroll
        for (int ni = 0; ni < 4; ++ni)
            bb[ni] = *reinterpret_cast<const short8*>(&wb[gl * 512 + (ni * 16 + c) * 8]);
        asm volatile("s_waitcnt lgkmcnt(0)" ::: "memory");
        __builtin_amdgcn_sched_barrier(0);
        if (tt <= 13) STAGE_G(10 + tt);
        short8 a[5];
        #pragma unroll
        for (int mi = 0; mi < 5; ++mi)
            a[mi] = *reinterpret_cast<const short8*>(
                &Hs[(mi * 16 + c) * 520 + tt * 32 + gl * 8]);
        #pragma unroll
        for (int mi = 0; mi < 5; ++mi)
            #pragma unroll
            for (int ni = 0; ni < 4; ++ni)
                acc[mi][ni] = __builtin_amdgcn_mfma_f32_16x16x32_bf16(a[mi], bb[ni], acc[mi][ni], 0, 0, 0);
    }
#undef STAGE_G

    // bias + squared row-sums (this wave's 64 cols of all 80 rows)
    float sq[5][4];
    {
        float bias2[4];
        #pragma unroll
        for (int ni = 0; ni < 4; ++ni) bias2[ni] = b2[s * CLIP + col0 + ni * 16 + c];
        #pragma unroll
        for (int mi = 0; mi < 5; ++mi)
            #pragma unroll
            for (int i = 0; i < 4; ++i) sq[mi][i] = 0.f;
        #pragma unroll
        for (int mi = 0; mi < 5; ++mi)
            #pragma unroll
            for (int ni = 0; ni < 4; ++ni)
                #pragma unroll
                for (int i = 0; i < 4; ++i) {
                    float v = acc[mi][ni][i] + bias2[ni];
                    acc[mi][ni][i] = v;
                    sq[mi][i] += v * v;
                }
    }
    #pragma unroll
    for (int m = 1; m < 16; m <<= 1)
        #pragma unroll
        for (int mi = 0; mi < 5; ++mi)
            #pragma unroll
            for (int i = 0; i < 4; ++i)
                sq[mi][i] += __shfl_xor(sq[mi][i], m);

    if (c == 0) {
        #pragma unroll
        for (int mi = 0; mi < 5; ++mi)
            #pragma unroll
            for (int i = 0; i < 4; ++i)
                partial[(mi * 16 + gl * 4 + i) * 8 + wave] = sq[mi][i];
    }
    __syncthreads();
    if (tid < 80) {
        float t = 0.f;
        #pragma unroll
        for (int w = 0; w < 8; ++w) t += partial[tid * 8 + w];
        scalev[tid] = 1.f / fmaxf(sqrtf(t), 1e-12f);
    }
    __syncthreads();

    #pragma unroll
    for (int mi = 0; mi < 5; ++mi)
        #pragma unroll
        for (int i = 0; i < 4; ++i) {
            int row = mi * 16 + gl * 4 + i;
            if (row < nrows) {
                float sc = scalev[row];
                float* op = out + (size_t)rowidx[row] * CLIP + col0 + c;
                #pragma unroll
                for (int ni = 0; ni < 4; ++ni)
                    __builtin_nontemporal_store(acc[mi][ni][i] * sc, op + ni * 16);
            }
        }
}

extern "C" void kernel_launch(void* const* d_in, const int* in_sizes, int n_in,
                              void* d_out, int out_size, void* d_ws, size_t ws_size,
                              hipStream_t stream) {
    const float* eeg = (const float*)d_in[0];
    const int* sid   = (const int*)d_in[1];
    const float* W1  = (const float*)d_in[2];
    const float* b1  = (const float*)d_in[3];
    const float* W2  = (const float*)d_in[4];
    const float* b2  = (const float*)d_in[5];
    float* out = (float*)d_out;

    u16* w1p = (u16*)d_ws;                                   // 3.4 MB (packed)
    u16* w2p = w1p + (size_t)NSUB * CLIP * EEG;              // 6.8 MB (packed)
    int* meta = (int*)(w2p + (size_t)NSUB * CLIP * CLIP);    // ~68 KB

    convert_pack<<<1248, 256, 0, stream>>>(W1, W2, w1p, w2p, sid, meta);
    scanscatter_k<<<64, 256, 0, stream>>>(sid, meta);
    mlp_k<<<BATCH / 80 + NSUB + 1, 512, 0, stream>>>(eeg, b1, b2, w1p, w2p, meta, out);
}

// Round 18
// 42.725 us; speedup vs baseline: 1.2019x; 1.0326x over previous
//
#include <hip/hip_runtime.h>
#include <hip/hip_bf16.h>

// SubjectSpecificProjection: per-subject 2-layer MLP (256->512->512) + L2 normalize.
// R18: R17 + (1) whole-X single stage (layer 1 fully barrier-free, 4 barriers
//      total vs 12 — each barrier synced 8 waves to slowest DMA); (2) counted
//      lgkmcnt(5) buffer-protect (a-read latency overlaps bb drain; LDS ops
//      complete in order). Depth-2 wave-private W DMA, vmcnt(4) steady state.

#define BATCH 16384
#define EEG 256
#define CLIP 512
#define NSUB 13

// meta layout (ints):
#define M_BCNT 0        // [64][13]
#define M_SOFF 832      // [14] sample offsets per subject
#define M_TOT  846      // [13]
#define M_C80  859      // [14] 80-row chunk offsets
#define M_IDX  896      // [16384]

typedef unsigned short u16;
typedef __attribute__((ext_vector_type(8))) short short8;
typedef __attribute__((ext_vector_type(4))) float f32x4;

__device__ __forceinline__ u16 f2bf(float f) {
    union { float f; unsigned int u; } v; v.f = f;
    unsigned int u = v.u;
    unsigned int r = (u + 0x7FFFu + ((u >> 16) & 1u)) >> 16;   // RNE
    return (u16)r;
}

__device__ __forceinline__ void raw_barrier_lgkm() {
    asm volatile("s_waitcnt lgkmcnt(0)" ::: "memory");
    __builtin_amdgcn_sched_barrier(0);
    __builtin_amdgcn_s_barrier();
    __builtin_amdgcn_sched_barrier(0);
}

// ---- weight convert + pack (R7 layout) + fused histogram ----
// chunk(s,g,t) = 2048 u16 [slot(4)][colin(64)][e(8)]; element =
//   W[s][k = t*32 + slot*8 + e][n = g*64 + colin].
__global__ __launch_bounds__(256) void convert_pack(
    const float* __restrict__ W1, const float* __restrict__ W2,
    u16* __restrict__ w1p, u16* __restrict__ w2p,
    const int* __restrict__ sid, int* __restrict__ meta) {
    __shared__ u16 T[64][72];
    __shared__ int hh[NSUB];
    int b = blockIdx.x;
    const float* src; u16* dstbase; int ksteps;
    int s, kt, g;
    if (b < 416) {                     // W1: 13 x (4 kt)x(8 g)
        s = b >> 5; int t = b & 31;
        kt = t >> 3; g = t & 7;
        ksteps = 8;
        src = W1 + (size_t)s * EEG * CLIP;
        dstbase = w1p + (size_t)s * CLIP * EEG;
    } else {                           // W2: 13 x (8 kt)x(8 g)
        b -= 416; s = b >> 6; int t = b & 63;
        kt = t >> 3; g = t & 7;
        ksteps = 16;
        src = W2 + (size_t)s * CLIP * CLIP;
        dstbase = w2p + (size_t)s * CLIP * CLIP;
    }
    int k0 = kt << 6, n0 = g << 6;
    int tid = threadIdx.x;
    int rk = tid >> 2;
    int cg = (tid & 3) << 4;
    const float4* p4 = reinterpret_cast<const float4*>(src + (size_t)(k0 + rk) * CLIP + n0 + cg);
    #pragma unroll
    for (int jj = 0; jj < 4; ++jj) {
        float4 v = p4[jj];
        T[cg + jj * 4 + 0][rk] = f2bf(v.x);
        T[cg + jj * 4 + 1][rk] = f2bf(v.y);
        T[cg + jj * 4 + 2][rk] = f2bf(v.z);
        T[cg + jj * 4 + 3][rk] = f2bf(v.w);
    }
    __syncthreads();
    int colin = tid & 63, sl = (tid >> 6) & 3;
    #pragma unroll
    for (int half = 0; half < 2; ++half) {
        int t = kt * 2 + half;
        u16* dst = dstbase + ((size_t)(g * ksteps + t)) * 2048 + sl * 512 + colin * 8;
        *reinterpret_cast<short8*>(dst) =
            *reinterpret_cast<const short8*>(&T[colin][half * 32 + sl * 8]);
    }
    if (blockIdx.x < 64) {             // fused histogram
        if (tid < NSUB) hh[tid] = 0;
        __syncthreads();
        atomicAdd(&hh[sid[blockIdx.x * 256 + tid]], 1);
        __syncthreads();
        if (tid < NSUB) meta[M_BCNT + blockIdx.x * NSUB + tid] = hh[tid];
    }
}

// ---- scan + scatter in one kernel ----
__global__ __launch_bounds__(256) void scanscatter_k(
    const int* __restrict__ sid, int* __restrict__ meta) {
    __shared__ int cnt[64][NSUB];
    __shared__ int so[NSUB + 1], myoff[NSUB], tot[NSUB];
    __shared__ int h[NSUB];
    int tid = threadIdx.x;
    for (int i = tid; i < 64 * NSUB; i += 256)
        cnt[i / NSUB][i % NSUB] = meta[M_BCNT + i];
    if (tid < NSUB) h[tid] = 0;
    __syncthreads();
    if (tid < NSUB) {
        int run = 0, mine = 0;
        for (int b = 0; b < 64; ++b) {
            if (b == (int)blockIdx.x) mine = run;
            run += cnt[b][tid];
        }
        tot[tid] = run; myoff[tid] = mine;
    }
    __syncthreads();
    if (tid == 0) {
        int off = 0;
        for (int s = 0; s < NSUB; ++s) { so[s] = off; off += tot[s]; }
        so[NSUB] = off;
    }
    __syncthreads();
    if (blockIdx.x == 0) {
        if (tid < NSUB + 1) meta[M_SOFF + tid] = so[tid];
        if (tid < NSUB) meta[M_TOT + tid] = tot[tid];
        if (tid == 0) {
            int c80 = 0;
            for (int s = 0; s < NSUB; ++s) {
                meta[M_C80 + s] = c80;
                c80 += (tot[s] + 79) / 80;
            }
            meta[M_C80 + NSUB] = c80;
        }
    }
    int i = blockIdx.x * 256 + tid;
    int s = sid[i];
    int r = atomicAdd(&h[s], 1);
    meta[M_IDX + so[s] + myoff[s] + r] = i;
}

// ---- fused MLP: M=80, 512 thr / 8 waves x 64 cols, depth-2 wave-private W DMA,
//      4 barriers total ----
__global__ __launch_bounds__(512) void mlp_k(
    const float* __restrict__ X, const float* __restrict__ b1,
    const float* __restrict__ b2, const u16* __restrict__ w1p,
    const u16* __restrict__ w2p, const int* __restrict__ meta,
    float* __restrict__ out) {

    __shared__ u16 Hs[80 * 520];       // 83.2 KB; head doubles as Xc[80][264]
    __shared__ u16 Wl[8 * 4096];       // 64 KB: wave-private 2x4KB double buffer
    __shared__ float partial[80 * 8];  // 2.5 KB
    __shared__ float scalev[80];
    __shared__ int info[4];
    __shared__ int rowidx[80];
    __shared__ int cobuf[14], sobuf[14], totbuf[NSUB];

    int tid = threadIdx.x;

    // bijective XCD swizzle (m204)
    int nwg = gridDim.x;
    int q = nwg >> 3, r = nwg & 7;
    int xcd = blockIdx.x & 7, idx = blockIdx.x >> 3;
    int bid = (xcd < r) ? xcd * (q + 1) + idx : r * (q + 1) + (xcd - r) * q + idx;

    if (tid < 14) { cobuf[tid] = meta[M_C80 + tid]; sobuf[tid] = meta[M_SOFF + tid]; }
    if (tid < NSUB) totbuf[tid] = meta[M_TOT + tid];
    __syncthreads();
    if (tid == 0) {
        int total = cobuf[NSUB];
        if (bid < total) {
            int s = 0;
            while (s < NSUB && !(bid >= cobuf[s] && bid < cobuf[s + 1])) s++;
            int chunk = bid - cobuf[s];
            info[0] = s;
            info[1] = sobuf[s] + chunk * 80;
            info[2] = min(80, totbuf[s] - chunk * 80);
        } else info[0] = -1;
    }
    __syncthreads();
    if (info[0] < 0) return;
    int s = info[0], rowbase = info[1], nrows = info[2];
    if (tid < 80) rowidx[tid] = meta[M_IDX + rowbase + min(tid, nrows - 1)];

    int wave = tid >> 6, lane = tid & 63;
    int c = lane & 15, gl = lane >> 4;
    int col0 = wave * 64;              // this wave's 64 cols (both layers)
    const u16* w1c = w1p + (size_t)s * CLIP * EEG + (size_t)wave * 8 * 2048;
    const u16* w2c = w2p + (size_t)s * CLIP * CLIP + (size_t)wave * 16 * 2048;
    u16* wl = &Wl[wave * 4096];        // wave-private: 2 bufs x 2048 u16

    // stage global stage g (0..23) into buf g&1
#define STAGE_G(g) do {                                                          \
        const u16* _src = ((g) < 8) ? (w1c + (size_t)(g) * 2048)                 \
                                    : (w2c + (size_t)((g) - 8) * 2048);          \
        u16* _dst = wl + (((g) & 1) ? 2048 : 0);                                 \
        _Pragma("unroll")                                                        \
        for (int _it = 0; _it < 4; ++_it)                                        \
            __builtin_amdgcn_global_load_lds(                                    \
                (const __attribute__((address_space(1))) unsigned int*)          \
                    (_src + _it * 512 + lane * 8),                               \
                (__attribute__((address_space(3))) unsigned int*)(_dst + _it * 512), \
                16, 0, 0);                                                       \
    } while (0)

    // prologue: stages 0,1 in flight (8 vmem ops)
    STAGE_G(0);
    STAGE_G(1);

    u16* Xc = Hs;                      // alias [80][264]; temporally separated

    raw_barrier_lgkm();                // barrier 1: rowidx visible

    // ---- stage the WHOLE X tile once (barrier-free afterwards) ----
    if (tid < 320) {                   // 80 rows x 4 thr/row
        int srow = tid >> 2, sq4 = tid & 3;
        const float4* xp = reinterpret_cast<const float4*>(
            X + (size_t)rowidx[srow] * EEG);
        u16* xd = &Xc[srow * 264];
        #pragma unroll
        for (int kc = 0; kc < 4; ++kc) {
            #pragma unroll
            for (int j = 0; j < 4; ++j) {
                float4 v = xp[kc * 16 + sq4 * 4 + j];
                union { u16 u[4]; uint2 qq; } pk;
                pk.u[0] = f2bf(v.x); pk.u[1] = f2bf(v.y);
                pk.u[2] = f2bf(v.z); pk.u[3] = f2bf(v.w);
                *reinterpret_cast<uint2*>(&xd[kc * 64 + sq4 * 16 + j * 4]) = pk.qq;
            }
        }
    }
    raw_barrier_lgkm();                // barrier 2: X visible

    f32x4 acc[5][4];
    #pragma unroll
    for (int mi = 0; mi < 5; ++mi)
        #pragma unroll
        for (int ni = 0; ni < 4; ++ni)
            acc[mi][ni] = (f32x4){0.f, 0.f, 0.f, 0.f};

    // ---- layer 1: 8 pipelined steps, zero barriers ----
    #pragma unroll
    for (int t = 0; t < 8; ++t) {
        asm volatile("s_waitcnt vmcnt(4)" ::: "memory");   // stage t landed
        __builtin_amdgcn_sched_barrier(0);
        short8 bb[4];
        u16* wb = wl + ((t & 1) ? 2048 : 0);
        #pragma unroll
        for (int ni = 0; ni < 4; ++ni)
            bb[ni] = *reinterpret_cast<const short8*>(&wb[gl * 512 + (ni * 16 + c) * 8]);
        __builtin_amdgcn_sched_barrier(0);                 // pin bb before a
        short8 a[5];
        #pragma unroll
        for (int mi = 0; mi < 5; ++mi)
            a[mi] = *reinterpret_cast<const short8*>(
                &Xc[(mi * 16 + c) * 264 + t * 32 + gl * 8]);
        __builtin_amdgcn_sched_barrier(0);
        asm volatile("s_waitcnt lgkmcnt(5)" ::: "memory"); // bb (oldest 4) done
        __builtin_amdgcn_sched_barrier(0);
        STAGE_G(t + 2);                                    // overwrite buf t&1
        #pragma unroll
        for (int mi = 0; mi < 5; ++mi)
            #pragma unroll
            for (int ni = 0; ni < 4; ++ni)
                acc[mi][ni] = __builtin_amdgcn_mfma_f32_16x16x32_bf16(a[mi], bb[ni], acc[mi][ni], 0, 0, 0);
    }
    raw_barrier_lgkm();                // barrier 3: all Xc reads done

    // bias + relu -> Hs (stride 520); W2 stages 8,9 in flight across barriers
    {
        float bias1[4];
        #pragma unroll
        for (int ni = 0; ni < 4; ++ni) bias1[ni] = b1[s * CLIP + col0 + ni * 16 + c];
        #pragma unroll
        for (int mi = 0; mi < 5; ++mi)
            #pragma unroll
            for (int ni = 0; ni < 4; ++ni)
                #pragma unroll
                for (int i = 0; i < 4; ++i) {
                    float h = fmaxf(acc[mi][ni][i] + bias1[ni], 0.f);
                    Hs[(mi * 16 + gl * 4 + i) * 520 + col0 + ni * 16 + c] = f2bf(h);
                }
    }
    raw_barrier_lgkm();                // barrier 4: Hs visible

    // ---- layer 2: 16 pipelined steps, zero barriers ----
    #pragma unroll
    for (int mi = 0; mi < 5; ++mi)
        #pragma unroll
        for (int ni = 0; ni < 4; ++ni)
            acc[mi][ni] = (f32x4){0.f, 0.f, 0.f, 0.f};

    for (int tt = 0; tt < 16; ++tt) {  // consumes global stage 8+tt
        if (tt < 15) asm volatile("s_waitcnt vmcnt(4)" ::: "memory");
        else         asm volatile("s_waitcnt vmcnt(0)" ::: "memory");
        __builtin_amdgcn_sched_barrier(0);
        short8 bb[4];
        u16* wb = wl + ((tt & 1) ? 2048 : 0);   // (8+tt)&1 == tt&1
        #pragma unroll
        for (int ni = 0; ni < 4; ++ni)
            bb[ni] = *reinterpret_cast<const short8*>(&wb[gl * 512 + (ni * 16 + c) * 8]);
        __builtin_amdgcn_sched_barrier(0);                 // pin bb before a
        short8 a[5];
        #pragma unroll
        for (int mi = 0; mi < 5; ++mi)
            a[mi] = *reinterpret_cast<const short8*>(
                &Hs[(mi * 16 + c) * 520 + tt * 32 + gl * 8]);
        __builtin_amdgcn_sched_barrier(0);
        asm volatile("s_waitcnt lgkmcnt(5)" ::: "memory"); // bb done
        __builtin_amdgcn_sched_barrier(0);
        if (tt <= 13) STAGE_G(10 + tt);
        #pragma unroll
        for (int mi = 0; mi < 5; ++mi)
            #pragma unroll
            for (int ni = 0; ni < 4; ++ni)
                acc[mi][ni] = __builtin_amdgcn_mfma_f32_16x16x32_bf16(a[mi], bb[ni], acc[mi][ni], 0, 0, 0);
    }
#undef STAGE_G

    // bias + squared row-sums (this wave's 64 cols of all 80 rows)
    float sq[5][4];
    {
        float bias2[4];
        #pragma unroll
        for (int ni = 0; ni < 4; ++ni) bias2[ni] = b2[s * CLIP + col0 + ni * 16 + c];
        #pragma unroll
        for (int mi = 0; mi < 5; ++mi)
            #pragma unroll
            for (int i = 0; i < 4; ++i) sq[mi][i] = 0.f;
        #pragma unroll
        for (int mi = 0; mi < 5; ++mi)
            #pragma unroll
            for (int ni = 0; ni < 4; ++ni)
                #pragma unroll
                for (int i = 0; i < 4; ++i) {
                    float v = acc[mi][ni][i] + bias2[ni];
                    acc[mi][ni][i] = v;
                    sq[mi][i] += v * v;
                }
    }
    #pragma unroll
    for (int m = 1; m < 16; m <<= 1)
        #pragma unroll
        for (int mi = 0; mi < 5; ++mi)
            #pragma unroll
            for (int i = 0; i < 4; ++i)
                sq[mi][i] += __shfl_xor(sq[mi][i], m);

    if (c == 0) {
        #pragma unroll
        for (int mi = 0; mi < 5; ++mi)
            #pragma unroll
            for (int i = 0; i < 4; ++i)
                partial[(mi * 16 + gl * 4 + i) * 8 + wave] = sq[mi][i];
    }
    __syncthreads();
    if (tid < 80) {
        float t = 0.f;
        #pragma unroll
        for (int w = 0; w < 8; ++w) t += partial[tid * 8 + w];
        scalev[tid] = 1.f / fmaxf(sqrtf(t), 1e-12f);
    }
    __syncthreads();

    #pragma unroll
    for (int mi = 0; mi < 5; ++mi)
        #pragma unroll
        for (int i = 0; i < 4; ++i) {
            int row = mi * 16 + gl * 4 + i;
            if (row < nrows) {
                float sc = scalev[row];
                float* op = out + (size_t)rowidx[row] * CLIP + col0 + c;
                #pragma unroll
                for (int ni = 0; ni < 4; ++ni)
                    __builtin_nontemporal_store(acc[mi][ni][i] * sc, op + ni * 16);
            }
        }
}

extern "C" void kernel_launch(void* const* d_in, const int* in_sizes, int n_in,
                              void* d_out, int out_size, void* d_ws, size_t ws_size,
                              hipStream_t stream) {
    const float* eeg = (const float*)d_in[0];
    const int* sid   = (const int*)d_in[1];
    const float* W1  = (const float*)d_in[2];
    const float* b1  = (const float*)d_in[3];
    const float* W2  = (const float*)d_in[4];
    const float* b2  = (const float*)d_in[5];
    float* out = (float*)d_out;

    u16* w1p = (u16*)d_ws;                                   // 3.4 MB (packed)
    u16* w2p = w1p + (size_t)NSUB * CLIP * EEG;              // 6.8 MB (packed)
    int* meta = (int*)(w2p + (size_t)NSUB * CLIP * CLIP);    // ~68 KB

    convert_pack<<<1248, 256, 0, stream>>>(W1, W2, w1p, w2p, sid, meta);
    scanscatter_k<<<64, 256, 0, stream>>>(sid, meta);
    mlp_k<<<BATCH / 80 + NSUB + 1, 512, 0, stream>>>(eeg, b1, b2, w1p, w2p, meta, out);
}